// Round 9
// baseline (187.337 us; speedup 1.0000x reference)
//
#include <hip/hip_runtime.h>
#include <cstdint>
#include <cstddef>

#define M_TOT 16384   // B*S = 4*4096
#define K_DIM 2048    // H
#define N_HALF 1024   // H/2
#define NT 32         // K tiles of BK=64
#define L2T 0.012976281620653759f  // log2(10000)/1024

typedef short bf16x8 __attribute__((ext_vector_type(8)));
typedef float f32x16 __attribute__((ext_vector_type(16)));
typedef unsigned short u16x4 __attribute__((ext_vector_type(4)));

__device__ __forceinline__ unsigned short f2bf(float f) {
    unsigned int u = __builtin_bit_cast(unsigned int, f);
    u += 0x7fffu + ((u >> 16) & 1u);   // RNE (no NaN inputs)
    return (unsigned short)(u >> 16);
}

// One launch converts both x and W (fp32 -> bf16), grid-stride.
__global__ __launch_bounds__(256) void cvt_f32_bf16_2(const float4* __restrict__ inA,
                                                      u16x4* __restrict__ outA, int n4A,
                                                      const float4* __restrict__ inB,
                                                      u16x4* __restrict__ outB, int n4B) {
    int idx = blockIdx.x * 256 + threadIdx.x;
    int stride = gridDim.x * 256;
    int tot = n4A + n4B;
    for (int i = idx; i < tot; i += stride) {
        const float4 v = (i < n4A) ? inA[i] : inB[i - n4A];
        u16x4 o;
        o.x = f2bf(v.x); o.y = f2bf(v.y); o.z = f2bf(v.z); o.w = f2bf(v.w);
        if (i < n4A) outA[i] = o; else outB[i - n4A] = o;
    }
}

#define GLD16(g, l) __builtin_amdgcn_global_load_lds( \
    (const __attribute__((address_space(1))) void*)(g), \
    (__attribute__((address_space(3))) void*)(l), 16, 0, 0)

#define MFMA32(a, b, c) __builtin_amdgcn_mfma_f32_32x32x16_bf16((a), (b), (c), 0, 0, 0)
#define VMCNT4 asm volatile("s_waitcnt vmcnt(4)" ::: "memory")
#define LGK0   asm volatile("s_waitcnt lgkmcnt(0)" ::: "memory")
#define LGK8   asm volatile("s_waitcnt lgkmcnt(8)" ::: "memory")
#define BAR    __builtin_amdgcn_s_barrier()
#define SCHED0 __builtin_amdgcn_sched_barrier(0)

// R8 skeleton (proven: per-phase [reads; stage->nbuf; vmcnt(4); (lgkm8);
// BAR; lgkm0; MFMA]) with the MFMA shape switched to 32x32x16 bf16:
// per wave 4x2 tiles of 32x32 (rows 128, cols 32 low + 32 high paired),
// 8 MFMA per phase (half the instructions, +15% pipe ceiling).
// Stage units/regions and ds_read byte counts are IDENTICAL to R8.
__global__ __launch_bounds__(512, 2)
void gemm_rope(const unsigned short* __restrict__ Xb,
               const unsigned short* __restrict__ Wb,
               const float* __restrict__ bias,
               float* __restrict__ out)
{
    __shared__ __align__(16) unsigned short As[2][256][64];  // 64 KiB
    __shared__ __align__(16) unsigned short Bs[2][256][64];  // 64 KiB

    const int tid  = threadIdx.x;
    const int lane = tid & 63;
    const int wave = tid >> 6;
    const int wr = wave >> 2;   // 0..1  (row half)
    const int wc = wave & 3;    // 0..3  (col quarter)
    const int cl = lane & 31;   // row/col within 32-tile
    const int hi2 = lane >> 5;  // 0..1

    // XCD-aware swizzle (grid=512, 512%8==0 -> bijective)
    const int bid = blockIdx.x;
    const int swz = (bid & 7) * 64 + (bid >> 3);
    const int nb = swz & 7;     // 8 col-pair blocks of 128
    const int mb = swz >> 3;    // 64 row blocks of 256
    const int m0 = mb * 256;
    const int c0 = nb * 128;

    // ---- staging address precompute (linear LDS dst, swizzled global src) ----
    const unsigned short* aSrc[2][2];
    const unsigned short* bSrc[2][2];
    int aDst[2][2], bDst[2][2];
    #pragma unroll
    for (int l = 0; l < 2; ++l) {
        const int c = wave * 128 + l * 64 + lane;       // 16B-chunk index, 0..1023
        // A-unit(qi): rows {qi*64+[0,64)} U {128+qi*64+[0,64)}
        const int seg = c >> 9, within = c & 511;
        const int ris = within >> 3, cch = within & 7;
        const int kch = cch ^ (ris & 7);
        #pragma unroll
        for (int qi = 0; qi < 2; ++qi) {
            const int ldsrow = seg * 128 + qi * 64 + ris;
            aDst[qi][l] = ldsrow * 128 + cch * 16;
            const int grow = m0 + seg * 128 + qi * 64 + ris;
            aSrc[qi][l] = Xb + (size_t)grow * K_DIM + kch * 8;
        }
        // B-unit(qj): rows qj*128+[0,128)
        const int rin = c >> 3, cchb = c & 7;
        const int kchb = cchb ^ (rin & 7);
        #pragma unroll
        for (int qj = 0; qj < 2; ++qj) {
            bDst[qj][l] = (qj * 128 + rin) * 128 + cchb * 16;
            const int wrow = qj * N_HALF + c0 + rin;
            bSrc[qj][l] = Wb + (size_t)wrow * K_DIM + kchb * 8;
        }
    }

#define STAGE_A(q, bb, kk) do { \
    GLD16(aSrc[q][0] + (size_t)(kk) * 64, (char*)&As[bb][0][0] + aDst[q][0]); \
    GLD16(aSrc[q][1] + (size_t)(kk) * 64, (char*)&As[bb][0][0] + aDst[q][1]); \
} while (0)
#define STAGE_B(q, bb, kk) do { \
    GLD16(bSrc[q][0] + (size_t)(kk) * 64, (char*)&Bs[bb][0][0] + bDst[q][0]); \
    GLD16(bSrc[q][1] + (size_t)(kk) * 64, (char*)&Bs[bb][0][0] + bDst[q][1]); \
} while (0)

    // frag-read swizzled k byte-offsets within a 128-B LDS row.
    // 32x32x16 operand: row = lane&31, k = (lane>>5)*8 + j; k-step s adds 16.
    const int xorv = (cl & 7) << 4;
    int kb[4];
    #pragma unroll
    for (int s = 0; s < 4; ++s) kb[s] = (s * 32 + hi2 * 16) ^ xorv;

    f32x16 acc[4][2];
    #pragma unroll
    for (int i = 0; i < 4; ++i)
        #pragma unroll
        for (int j = 0; j < 2; ++j)
            acc[i][j] = (f32x16)(0.f);

    bf16x8 aF[2][4], bX[4], bY[4];

#define READ_A2(bb, rb) do { _Pragma("unroll") \
    for (int rtl = 0; rtl < 2; ++rtl) { _Pragma("unroll") \
      for (int s = 0; s < 4; ++s) \
        aF[rtl][s] = *(const bf16x8*)((const char*)&As[bb][0][0] + ((rb) + rtl * 32 + cl) * 128 + kb[s]); } } while (0)
#define READ_B4(dst, bb, rb) do { _Pragma("unroll") \
    for (int s = 0; s < 4; ++s) \
        dst[s] = *(const bf16x8*)((const char*)&Bs[bb][0][0] + ((rb) + cl) * 128 + kb[s]); } while (0)
#define CLUSTER(r0, bset, ct) do { \
    __builtin_amdgcn_s_setprio(1); \
    _Pragma("unroll") for (int s = 0; s < 4; ++s) { \
        acc[(r0)][ct]     = MFMA32(aF[0][s], bset[s], acc[(r0)][ct]); \
        acc[(r0) + 1][ct] = MFMA32(aF[1][s], bset[s], acc[(r0) + 1][ct]); } \
    __builtin_amdgcn_s_setprio(0); } while (0)

    // ---- prologue: tile 0 -> buf 0, unit order A0,B0,B1,A1 ----
    STAGE_A(0, 0, 0); STAGE_B(0, 0, 0); STAGE_B(1, 0, 0); STAGE_A(1, 0, 0);
    VMCNT4;   // A0,B0 of tile 0 landed (B1,A1 may be in flight)
    BAR;

    for (int kt = 0; kt < NT; ++kt) {
        const int buf = kt & 1, nbuf = buf ^ 1;
        const int kp1 = (kt + 1 < NT) ? kt + 1 : NT - 1;  // clamped: harmless dead stage at tail

        // ---- phase 0: read A(rt0,rt1)+B(low) [12]; stage A0(kt+1)->nbuf; MFMA acc[0..1][0] ----
        {
            READ_A2(buf, wr * 128);
            READ_B4(bX, buf, wc * 32);
            STAGE_A(0, nbuf, kp1);
            VMCNT4; LGK8; BAR; LGK0; SCHED0;
            CLUSTER(0, bX, 0);
        }
        // ---- phase 1: read B(high) [4]; stage B0(kt+1)->nbuf; MFMA acc[0..1][1] ----
        {
            READ_B4(bY, buf, 128 + wc * 32);
            STAGE_B(0, nbuf, kp1);
            VMCNT4; BAR; LGK0; SCHED0;
            CLUSTER(0, bY, 1);
        }
        // ---- phase 2: read A(rt2,rt3) [8]; stage B1(kt+1)->nbuf; MFMA acc[2..3][0] ----
        {
            READ_A2(buf, wr * 128 + 64);
            STAGE_B(1, nbuf, kp1);
            VMCNT4; BAR; LGK0; SCHED0;
            CLUSTER(2, bX, 0);
        }
        // ---- phase 3: stage A1(kt+1)->nbuf; MFMA acc[2..3][1] ----
        {
            STAGE_A(1, nbuf, kp1);
            VMCNT4; BAR; SCHED0;
            CLUSTER(2, bY, 1);
        }
    }
    asm volatile("s_waitcnt vmcnt(0)" ::: "memory");  // drain LDS-DMA before epilogue

    // ---- epilogue: bias + RoPE + 2x, fp32 store ----
    // acc[rt][0]: col ol = c0 + wc*32 + cl (low); acc[rt][1]: col ol+1024.
    // C mapping (32x32): col = lane&31, row = (reg&3) + 8*(reg>>2) + 4*(lane>>5).
    // Row walk per reg: +1, except +5 when (reg&3)==3 (also covers tile jumps).
    const int ol = c0 + wc * 32 + cl;
    const float invf = exp2f(-L2T * (float)ol);
    const float bl = bias[ol], bh = bias[ol + N_HALF];
    const float fs0 = (float)((m0 + wr * 128 + 4 * hi2) & 4095);
    float cs, sn, c1, s1, c5, s5;
    sincosf(fs0 * invf, &sn, &cs);     // base angle (row offset 0)
    sincosf(invf, &s1, &c1);           // +1 row step
    sincosf(5.0f * invf, &s5, &c5);    // +5 row step
    #pragma unroll
    for (int rt = 0; rt < 4; ++rt) {
        #pragma unroll
        for (int reg = 0; reg < 16; ++reg) {
            const int m = m0 + wr * 128 + rt * 32 + (reg & 3) + 8 * (reg >> 2) + 4 * hi2;
            float* orow = out + (size_t)m * K_DIM + ol;
            const float ql = acc[rt][0][reg] + bl;
            const float qh = acc[rt][1][reg] + bh;
            orow[0]      = 2.0f * (ql * cs - qh * sn);
            orow[N_HALF] = 2.0f * (qh * cs + ql * sn);
            float nc, ns;
            if ((reg & 3) == 3) { nc = cs * c5 - sn * s5; ns = sn * c5 + cs * s5; }
            else                { nc = cs * c1 - sn * s1; ns = sn * c1 + cs * s1; }
            cs = nc; sn = ns;
        }
    }
}

// Emergency fallback if workspace is too small: slow but correct fp32 path.
__global__ __launch_bounds__(256) void fallback_fused(const float* __restrict__ x,
                                                      const float* __restrict__ W,
                                                      const float* __restrict__ bias,
                                                      float* __restrict__ out)
{
    __shared__ float xs[K_DIM];
    const int m = blockIdx.x;
    const int tid = threadIdx.x;
    for (int k = tid; k < K_DIM; k += 256) xs[k] = x[(size_t)m * K_DIM + k];
    __syncthreads();
    const float fs = (float)(m & 4095);
    for (int ol = tid; ol < N_HALF; ol += 256) {
        const float* wl = W + (size_t)ol * K_DIM;
        const float* wh = W + (size_t)(ol + N_HALF) * K_DIM;
        float al = 0.f, ah = 0.f;
        for (int k = 0; k < K_DIM; ++k) { al += xs[k] * wl[k]; ah += xs[k] * wh[k]; }
        al += bias[ol]; ah += bias[ol + N_HALF];
        float sn, cs;
        sincosf(fs * exp2f(-L2T * (float)ol), &sn, &cs);
        out[(size_t)m * K_DIM + ol]          = 2.0f * (al * cs - ah * sn);
        out[(size_t)m * K_DIM + ol + N_HALF] = 2.0f * (ah * cs + al * sn);
    }
}

extern "C" void kernel_launch(void* const* d_in, const int* in_sizes, int n_in,
                              void* d_out, int out_size, void* d_ws, size_t ws_size,
                              hipStream_t stream)
{
    const float* x = (const float*)d_in[0];
    const float* W = (const float*)d_in[1];
    const float* b = (const float*)d_in[2];
    float* out = (float*)d_out;

    const size_t nx = (size_t)M_TOT * K_DIM;
    const size_t nw = (size_t)K_DIM * K_DIM;
    const size_t need = (nx + nw) * sizeof(unsigned short);
    if (ws_size < need) {
        fallback_fused<<<M_TOT, 256, 0, stream>>>(x, W, b, out);
        return;
    }
    unsigned short* xb = (unsigned short*)d_ws;
    unsigned short* wb = xb + nx;
    cvt_f32_bf16_2<<<2048, 256, 0, stream>>>((const float4*)x, (u16x4*)xb, (int)(nx / 4),
                                             (const float4*)W, (u16x4*)wb, (int)(nw / 4));
    gemm_rope<<<(M_TOT / 256) * (N_HALF / 128), 512, 0, stream>>>(xb, wb, b, out);
}